// Round 5
// baseline (280.811 us; speedup 1.0000x reference)
//
#include <hip/hip_runtime.h>
#include <math.h>

#define C 512
#define NPIX 4096   // 64*64
#define BATCH 16
#define O 512
#define R 6
#define LN_EPS 1e-5f
#define ATTN_OFF 16384   // float offset of attn[b][r][n] in ws

typedef float vf4 __attribute__((ext_vector_type(4)));

// ws layout (floats):
// [0, 4096)     wpsiT[c*8 + r] = ln_w[c]*psi[r,c]   (r<6; pads 6,7 unused)
// [4096, 4104)  swp[r] = sum_c ln_w[c]*psi[r,c]
// [4104, 4112)  sbp[r] = sum_c ln_b[c]*psi[r,c]
// [4112, 8208)  M[o*8 + r] = sum_c psi[r,c]*fc_w[o,c] + fc_b[o]  (pads 6,7 unused)
// [16384, 409600) attn[b*6*4096 + r*4096 + n]
//
// Stats partials are staged INSIDE out: out[b][g*8+st][n] for g<16, st<8
// (stream-ordered: combine reads them before bcast overwrites all of out).

__device__ __forceinline__ void hermite_rows(int c, float rows[R]) {
    float t = -1.0f + 2.0f * (float)c / 511.0f;
    float xd = tanhf(t) * 4.31662479035539984911f;  // sqrt(11)+1
    float g = expf(-0.5f * xd * xd);
    const float pi_m14 = 0.75112554446494248286f;   // pi^-0.25
    rows[0] = pi_m14 * g;
    rows[1] = 1.41421356237309504880f * pi_m14 * xd * g;
    #pragma unroll
    for (int k = 2; k <= 5; ++k)
        rows[k] = sqrtf(2.0f / k) * xd * rows[k - 1] - sqrtf((k - 1.0f) / k) * rows[k - 2];
}

// One dispatch for ALL setup. Blocks 0..511: M row o. Block 512: wpsiT + swp/sbp.
__global__ __launch_bounds__(64) void setup_all(const float* __restrict__ lnw,
                                                const float* __restrict__ lnb,
                                                const float* __restrict__ fcw,
                                                const float* __restrict__ fcb,
                                                float* __restrict__ ws) {
    const int o = blockIdx.x;
    const int l = threadIdx.x;
    if (o < O) {
        float acc[R] = {0.f, 0.f, 0.f, 0.f, 0.f, 0.f};
        #pragma unroll
        for (int k = 0; k < 8; ++k) {
            int c = l + (k << 6);
            float rows[R];
            hermite_rows(c, rows);
            float w = fcw[o * C + c];
            #pragma unroll
            for (int r = 0; r < R; ++r) acc[r] += rows[r] * w;
        }
        #pragma unroll
        for (int r = 0; r < R; ++r)
            #pragma unroll
            for (int m = 32; m >= 1; m >>= 1) acc[r] += __shfl_xor(acc[r], m, 64);
        if (l == 0) {
            float bias = fcb[o];   // softmax weights sum to 1 -> fold bias into M
            float* M = ws + 4112 + o * 8;
            #pragma unroll
            for (int r = 0; r < R; ++r) M[r] = acc[r] + bias;
        }
    } else {
        float sw[R] = {0.f, 0.f, 0.f, 0.f, 0.f, 0.f};
        float sb[R] = {0.f, 0.f, 0.f, 0.f, 0.f, 0.f};
        #pragma unroll
        for (int k = 0; k < 8; ++k) {
            int c = l + (k << 6);
            float rows[R];
            hermite_rows(c, rows);
            float w = lnw[c], bb = lnb[c];
            float* dst = ws + c * 8;
            #pragma unroll
            for (int r = 0; r < R; ++r) {
                float rw = rows[r] * w;
                dst[r] = rw;
                sw[r] += rw;
                sb[r] += rows[r] * bb;
            }
        }
        #pragma unroll
        for (int r = 0; r < R; ++r) {
            #pragma unroll
            for (int m = 32; m >= 1; m >>= 1) {
                sw[r] += __shfl_xor(sw[r], m, 64);
                sb[r] += __shfl_xor(sb[r], m, 64);
            }
        }
        if (l == 0) {
            #pragma unroll
            for (int r = 0; r < R; ++r) { ws[4096 + r] = sw[r]; ws[4104 + r] = sb[r]; }
        }
    }
}

// Phase 1: CONTIGUOUS read stream. 256 blocks (16 b x 16 channel-groups) x
// 512 threads. Block (b,g) reads channels [32g, 32g+32) = 512 KB fully
// contiguous (vs the 1 KB @ 16 KB stride of all previous versions — the
// suspected DRAM-efficiency killer). 64 independent float4 loads/thread,
// partial stats for ALL 4096 px held in 64 VGPRs of accumulators; no LDS,
// no barrier. Partials stored into out[b][g*8+st][:] (overwritten later).
__global__ __launch_bounds__(512, 2) void stats_partial(const float* __restrict__ x,
                                                        const float* __restrict__ ws,
                                                        float* __restrict__ outp) {
    const int t = threadIdx.x;          // 512
    const int b = blockIdx.x >> 4;
    const int g = blockIdx.x & 15;
    const int c0 = g << 5;
    const float* xb = x + (((size_t)(b * C + c0)) << 12) + (t << 2);
    const float* wb = ws + ((size_t)c0 << 3);

    vf4 z = {0.f, 0.f, 0.f, 0.f};
    vf4 a00=z,a01=z,a02=z,a03=z,a04=z,a05=z,a06=z,a07=z;   // j=0: px 4t..4t+3
    vf4 a10=z,a11=z,a12=z,a13=z,a14=z,a15=z,a16=z,a17=z;   // j=1: px 2048+4t..

    #pragma unroll
    for (int cc = 0; cc < 32; ++cc) {
        const float* wr = wb + (cc << 3);   // block-uniform -> s_load
        float w0 = wr[0], w1 = wr[1], w2 = wr[2];
        float w3 = wr[3], w4 = wr[4], w5 = wr[5];
        vf4 x0 = *(const vf4*)(xb + ((size_t)cc << 12));
        vf4 x1 = *(const vf4*)(xb + ((size_t)cc << 12) + 2048);
        a00 += x0;       a10 += x1;
        a01 += x0 * x0;  a11 += x1 * x1;
        a02 += x0 * w0;  a12 += x1 * w0;
        a03 += x0 * w1;  a13 += x1 * w1;
        a04 += x0 * w2;  a14 += x1 * w2;
        a05 += x0 * w3;  a15 += x1 * w3;
        a06 += x0 * w4;  a16 += x1 * w4;
        a07 += x0 * w5;  a17 += x1 * w5;
    }

    float* pb = outp + (((size_t)(b * O + (g << 3))) << 12) + (t << 2);
    *(vf4*)(pb + (0 << 12)) = a00;  *(vf4*)(pb + (0 << 12) + 2048) = a10;
    *(vf4*)(pb + (1 << 12)) = a01;  *(vf4*)(pb + (1 << 12) + 2048) = a11;
    *(vf4*)(pb + (2 << 12)) = a02;  *(vf4*)(pb + (2 << 12) + 2048) = a12;
    *(vf4*)(pb + (3 << 12)) = a03;  *(vf4*)(pb + (3 << 12) + 2048) = a13;
    *(vf4*)(pb + (4 << 12)) = a04;  *(vf4*)(pb + (4 << 12) + 2048) = a14;
    *(vf4*)(pb + (5 << 12)) = a05;  *(vf4*)(pb + (5 << 12) + 2048) = a15;
    *(vf4*)(pb + (6 << 12)) = a06;  *(vf4*)(pb + (6 << 12) + 2048) = a16;
    *(vf4*)(pb + (7 << 12)) = a07;  *(vf4*)(pb + (7 << 12) + 2048) = a17;
}

// Phase 2: combine partials (L2/L3-hot, 33.5 MB) + LN + softmax -> attn in ws.
// 256 blocks (16 b x 16 px-groups of 256) x 256 threads, one px per thread.
__global__ __launch_bounds__(256) void combine_softmax(const float* __restrict__ outp,
                                                       const float* __restrict__ ws,
                                                       float* __restrict__ attn) {
    const int tid = threadIdx.x;
    const int b = blockIdx.x >> 4;
    const int n = ((blockIdx.x & 15) << 8) + tid;
    const float* pb = outp + (((size_t)(b * O)) << 12) + n;

    float v[8] = {0.f, 0.f, 0.f, 0.f, 0.f, 0.f, 0.f, 0.f};
    #pragma unroll
    for (int g = 0; g < 16; ++g)
        #pragma unroll
        for (int st = 0; st < 8; ++st)
            v[st] += pb[(size_t)((g << 3) + st) << 12];

    float mu = v[0] * (1.0f / 512.0f);
    float var = v[1] * (1.0f / 512.0f) - mu * mu;
    float rsig = rsqrtf(var + LN_EPS);
    const float invsq = 0.04419417382415922f;  // 1/sqrt(512)
    float sc[R], mx = -1e30f;
    #pragma unroll
    for (int r = 0; r < R; ++r) {
        float swp = ws[4096 + r], sbp = ws[4104 + r];
        sc[r] = ((v[2 + r] - mu * swp) * rsig + sbp) * invsq;
        mx = fmaxf(mx, sc[r]);
    }
    float es = 0.f, at[R];
    #pragma unroll
    for (int r = 0; r < R; ++r) { at[r] = expf(sc[r] - mx); es += at[r]; }
    float inv = 1.0f / es;
    #pragma unroll
    for (int r = 0; r < R; ++r)
        attn[(((size_t)(b * 6 + r)) << 12) + n] = at[r] * inv;
}

// Phase 3: pure write stream (round-0-proven). 4096 blocks (16 b x 4
// px-groups(1024) x 64 o-groups(8)) x 256 threads. Thread owns 4 px x 8
// o-rows; attn L2-served; M via uniform scalar loads; nontemporal stores.
__global__ __launch_bounds__(256) void bcast_kernel(const float* __restrict__ ws,
                                                    float* __restrict__ out) {
    const int tid = threadIdx.x;
    const int bid = blockIdx.x;
    const int b = bid >> 8;
    const int pxg = (bid >> 6) & 3;
    const int og = bid & 63;
    const int n = (pxg << 10) + (tid << 2);

    const float* attn = ws + ATTN_OFF;
    vf4 ar[R];
    #pragma unroll
    for (int r = 0; r < R; ++r)
        ar[r] = *(const vf4*)(attn + (((size_t)(b * 6 + r)) << 12) + n);

    float* ob = out + (((size_t)(b * O + (og << 3))) << 12) + n;
    #pragma unroll
    for (int j = 0; j < 8; ++j) {
        int o = (og << 3) + j;  // uniform -> M loads scalarize
        float m0 = ws[4112 + o * 8 + 0];
        float m1 = ws[4112 + o * 8 + 1];
        float m2 = ws[4112 + o * 8 + 2];
        float m3 = ws[4112 + o * 8 + 3];
        float m4 = ws[4112 + o * 8 + 4];
        float m5 = ws[4112 + o * 8 + 5];
        vf4 res = ar[0] * m0 + ar[1] * m1 + ar[2] * m2
                + ar[3] * m3 + ar[4] * m4 + ar[5] * m5;
        __builtin_nontemporal_store(res, (vf4*)(ob + ((size_t)j << 12)));
    }
}

extern "C" void kernel_launch(void* const* d_in, const int* in_sizes, int n_in,
                              void* d_out, int out_size, void* d_ws, size_t ws_size,
                              hipStream_t stream) {
    const float* x    = (const float*)d_in[0];
    const float* ln_w = (const float*)d_in[1];
    const float* ln_b = (const float*)d_in[2];
    const float* fc_w = (const float*)d_in[3];
    const float* fc_b = (const float*)d_in[4];
    float* out = (float*)d_out;
    float* ws = (float*)d_ws;

    setup_all<<<O + 1, 64, 0, stream>>>(ln_w, ln_b, fc_w, fc_b, ws);
    stats_partial<<<BATCH * 16, 512, 0, stream>>>(x, ws, out);
    combine_softmax<<<BATCH * 16, 256, 0, stream>>>(out, ws, ws + ATTN_OFF);
    bcast_kernel<<<4096, 256, 0, stream>>>(ws, out);
}

// Round 6
// 255.835 us; speedup vs baseline: 1.0976x; 1.0976x over previous
//
#include <hip/hip_runtime.h>
#include <math.h>

#define C 512
#define NPIX 4096   // 64*64
#define BATCH 16
#define O 512
#define R 6
#define LN_EPS 1e-5f

typedef float vf2 __attribute__((ext_vector_type(2)));

// ws layout (floats):
// [0, 4096)     wpsiT[c*8 + r] = ln_w[c]*psi[r,c]   (r<6; pads 6,7 unused)
// [4096, 4104)  swp[r] = sum_c ln_w[c]*psi[r,c]
// [4104, 4112)  sbp[r] = sum_c ln_b[c]*psi[r,c]
// [4112, 8208)  M[o*8 + r] = sum_c psi[r,c]*fc_w[o,c] + fc_b[o]  (pads 6,7 unused)

__device__ __forceinline__ void hermite_rows(int c, float rows[R]) {
    float t = -1.0f + 2.0f * (float)c / 511.0f;
    float xd = tanhf(t) * 4.31662479035539984911f;  // sqrt(11)+1
    float g = expf(-0.5f * xd * xd);
    const float pi_m14 = 0.75112554446494248286f;   // pi^-0.25
    rows[0] = pi_m14 * g;
    rows[1] = 1.41421356237309504880f * pi_m14 * xd * g;
    #pragma unroll
    for (int k = 2; k <= 5; ++k)
        rows[k] = sqrtf(2.0f / k) * xd * rows[k - 1] - sqrtf((k - 1.0f) / k) * rows[k - 2];
}

// One dispatch for ALL setup. Blocks 0..511: M row o. Block 512: wpsiT + swp/sbp.
__global__ __launch_bounds__(64) void setup_all(const float* __restrict__ lnw,
                                                const float* __restrict__ lnb,
                                                const float* __restrict__ fcw,
                                                const float* __restrict__ fcb,
                                                float* __restrict__ ws) {
    const int o = blockIdx.x;
    const int l = threadIdx.x;
    if (o < O) {
        float acc[R] = {0.f, 0.f, 0.f, 0.f, 0.f, 0.f};
        #pragma unroll
        for (int k = 0; k < 8; ++k) {
            int c = l + (k << 6);
            float rows[R];
            hermite_rows(c, rows);
            float w = fcw[o * C + c];
            #pragma unroll
            for (int r = 0; r < R; ++r) acc[r] += rows[r] * w;
        }
        #pragma unroll
        for (int r = 0; r < R; ++r)
            #pragma unroll
            for (int m = 32; m >= 1; m >>= 1) acc[r] += __shfl_xor(acc[r], m, 64);
        if (l == 0) {
            float bias = fcb[o];   // softmax weights sum to 1 -> fold bias into M
            float* M = ws + 4112 + o * 8;
            #pragma unroll
            for (int r = 0; r < R; ++r) M[r] = acc[r] + bias;
        }
    } else {
        float sw[R] = {0.f, 0.f, 0.f, 0.f, 0.f, 0.f};
        float sb[R] = {0.f, 0.f, 0.f, 0.f, 0.f, 0.f};
        #pragma unroll
        for (int k = 0; k < 8; ++k) {
            int c = l + (k << 6);
            float rows[R];
            hermite_rows(c, rows);
            float w = lnw[c], bb = lnb[c];
            float* dst = ws + c * 8;
            #pragma unroll
            for (int r = 0; r < R; ++r) {
                float rw = rows[r] * w;
                dst[r] = rw;
                sw[r] += rw;
                sb[r] += rows[r] * bb;
            }
        }
        #pragma unroll
        for (int r = 0; r < R; ++r) {
            #pragma unroll
            for (int m = 32; m >= 1; m >>= 1) {
                sw[r] += __shfl_xor(sw[r], m, 64);
                sb[r] += __shfl_xor(sb[r], m, 64);
            }
        }
        if (l == 0) {
            #pragma unroll
            for (int r = 0; r < R; ++r) { ws[4096 + r] = sw[r]; ws[4104 + r] = sb[r]; }
        }
    }
}

// Fused, write-behind pipelined: 256 blocks (16 b x 16 tiles of 256 px) x
// 1024 threads (16 waves). Tile = two 128-px halves h0,h1. Epoch order:
//   [read h0] [combine h0] [ISSUE write h0, regular stores -> L2]
//   [read h1 (overlaps h0's L2->HBM drain)] [combine h1] [write h1]
// The copy ubench proves 3.15 TB/s read + 3.15 TB/s write run CONCURRENTLY;
// previous versions serialized the directions (60us read epoch then 20us
// write epoch). Regular (non-nt) full-line stores absorb into L2 at L2
// speed and drain to HBM in the background under the next read epoch.
// No load/store vmcnt coupling (r4's failure): epochs are bulk-separated.
__global__ __launch_bounds__(1024, 4) void fused_kernel(const float* __restrict__ x,
                                                        const float* __restrict__ ws,
                                                        float* __restrict__ out) {
    __shared__ float part[16][8][128];  // [wave][stat][px], 64 KB
    __shared__ float attn_s[R][128];    // 3 KB
    const int tid = threadIdx.x;
    const int wv = tid >> 6;
    const int l = tid & 63;
    const int b = blockIdx.x >> 4;
    const int sg = blockIdx.x & 15;
    const int n0 = sg << 8;             // 256-px tile base
    const int p2 = l << 1;
    const int wuni = __builtin_amdgcn_readfirstlane(wv);  // force SGPR

    const float* xw = x + (((size_t)(b * C + (wuni << 5))) << 12);
    float* ow = out + (((size_t)(b * O + (wuni << 5))) << 12);
    const float* wbase = ws + ((size_t)(wuni << 5) << 3);
    const float* Ms = ws + 4112 + ((size_t)(wuni << 5) << 3);

    float sx, sy, ssx, ssy;
    float a0x, a0y, a1x, a1y, a2x, a2y, a3x, a3y, a4x, a4y, a5x, a5y;
    float arx[R], ary[R];

    // ================= epoch A: read h0 (px n0..n0+127) =================
    {
        const float* xb = xw + n0 + p2;
        sx = sy = ssx = ssy = 0.f;
        a0x = a0y = a1x = a1y = a2x = a2y = 0.f;
        a3x = a3y = a4x = a4y = a5x = a5y = 0.f;
        #pragma unroll
        for (int i = 0; i < 32; ++i) {
            vf2 xv = *(const vf2*)(xb + ((size_t)i << 12));
            const float* wr = wbase + (i << 3);     // wave-uniform -> s_load
            float w0 = wr[0], w1 = wr[1], w2 = wr[2];
            float w3 = wr[3], w4 = wr[4], w5 = wr[5];
            sx += xv.x;          sy += xv.y;
            ssx += xv.x * xv.x;  ssy += xv.y * xv.y;
            a0x += xv.x * w0;    a0y += xv.y * w0;
            a1x += xv.x * w1;    a1y += xv.y * w1;
            a2x += xv.x * w2;    a2y += xv.y * w2;
            a3x += xv.x * w3;    a3y += xv.y * w3;
            a4x += xv.x * w4;    a4y += xv.y * w4;
            a5x += xv.x * w5;    a5y += xv.y * w5;
        }
        vf2 t;
        t.x = sx;  t.y = sy;  *(vf2*)&part[wv][0][p2] = t;
        t.x = ssx; t.y = ssy; *(vf2*)&part[wv][1][p2] = t;
        t.x = a0x; t.y = a0y; *(vf2*)&part[wv][2][p2] = t;
        t.x = a1x; t.y = a1y; *(vf2*)&part[wv][3][p2] = t;
        t.x = a2x; t.y = a2y; *(vf2*)&part[wv][4][p2] = t;
        t.x = a3x; t.y = a3y; *(vf2*)&part[wv][5][p2] = t;
        t.x = a4x; t.y = a4y; *(vf2*)&part[wv][6][p2] = t;
        t.x = a5x; t.y = a5y; *(vf2*)&part[wv][7][p2] = t;
    }
    __syncthreads();

    // ---- combine + softmax h0 ----
    if (tid < 128) {
        float v[8];
        #pragma unroll
        for (int st = 0; st < 8; ++st) {
            float acc = 0.f;
            #pragma unroll
            for (int w = 0; w < 16; ++w) acc += part[w][st][tid];
            v[st] = acc;
        }
        float mu = v[0] * (1.0f / 512.0f);
        float var = v[1] * (1.0f / 512.0f) - mu * mu;
        float rsig = rsqrtf(var + LN_EPS);
        const float invsq = 0.04419417382415922f;  // 1/sqrt(512)
        float sc[R], mx = -1e30f;
        #pragma unroll
        for (int r = 0; r < R; ++r) {
            float swp = ws[4096 + r], sbp = ws[4104 + r];
            sc[r] = ((v[2 + r] - mu * swp) * rsig + sbp) * invsq;
            mx = fmaxf(mx, sc[r]);
        }
        float es = 0.f, at[R];
        #pragma unroll
        for (int r = 0; r < R; ++r) { at[r] = expf(sc[r] - mx); es += at[r]; }
        float inv = 1.0f / es;
        #pragma unroll
        for (int r = 0; r < R; ++r) attn_s[r][tid] = at[r] * inv;
    }
    __syncthreads();

    #pragma unroll
    for (int r = 0; r < R; ++r) {
        vf2 a = *(const vf2*)&attn_s[r][p2];
        arx[r] = a.x; ary[r] = a.y;
    }

    // ====== epoch B: ISSUE write h0 (regular stores -> L2, drain later) ======
    {
        float* ob = ow + n0 + p2;
        #pragma unroll
        for (int j = 0; j < 32; ++j) {
            const float* mo = Ms + (j << 3);        // wave-uniform -> s_load
            float m0 = mo[0], m1 = mo[1], m2 = mo[2];
            float m3 = mo[3], m4 = mo[4], m5 = mo[5];
            vf2 res;
            res.x = arx[0] * m0 + arx[1] * m1 + arx[2] * m2
                  + arx[3] * m3 + arx[4] * m4 + arx[5] * m5;
            res.y = ary[0] * m0 + ary[1] * m1 + ary[2] * m2
                  + ary[3] * m3 + ary[4] * m4 + ary[5] * m5;
            *(vf2*)(ob + ((size_t)j << 12)) = res;  // NOT nontemporal: L2-absorbed
        }
    }

    // ===== epoch C: read h1 (px n0+128..n0+255) — overlaps h0 store drain =====
    {
        const float* xb = xw + n0 + 128 + p2;
        sx = sy = ssx = ssy = 0.f;
        a0x = a0y = a1x = a1y = a2x = a2y = 0.f;
        a3x = a3y = a4x = a4y = a5x = a5y = 0.f;
        #pragma unroll
        for (int i = 0; i < 32; ++i) {
            vf2 xv = *(const vf2*)(xb + ((size_t)i << 12));
            const float* wr = wbase + (i << 3);     // wave-uniform -> s_load
            float w0 = wr[0], w1 = wr[1], w2 = wr[2];
            float w3 = wr[3], w4 = wr[4], w5 = wr[5];
            sx += xv.x;          sy += xv.y;
            ssx += xv.x * xv.x;  ssy += xv.y * xv.y;
            a0x += xv.x * w0;    a0y += xv.y * w0;
            a1x += xv.x * w1;    a1y += xv.y * w1;
            a2x += xv.x * w2;    a2y += xv.y * w2;
            a3x += xv.x * w3;    a3y += xv.y * w3;
            a4x += xv.x * w4;    a4y += xv.y * w4;
            a5x += xv.x * w5;    a5y += xv.y * w5;
        }
        vf2 t;
        t.x = sx;  t.y = sy;  *(vf2*)&part[wv][0][p2] = t;
        t.x = ssx; t.y = ssy; *(vf2*)&part[wv][1][p2] = t;
        t.x = a0x; t.y = a0y; *(vf2*)&part[wv][2][p2] = t;
        t.x = a1x; t.y = a1y; *(vf2*)&part[wv][3][p2] = t;
        t.x = a2x; t.y = a2y; *(vf2*)&part[wv][4][p2] = t;
        t.x = a3x; t.y = a3y; *(vf2*)&part[wv][5][p2] = t;
        t.x = a4x; t.y = a4y; *(vf2*)&part[wv][6][p2] = t;
        t.x = a5x; t.y = a5y; *(vf2*)&part[wv][7][p2] = t;
    }
    __syncthreads();

    // ---- combine + softmax h1 ----
    if (tid < 128) {
        float v[8];
        #pragma unroll
        for (int st = 0; st < 8; ++st) {
            float acc = 0.f;
            #pragma unroll
            for (int w = 0; w < 16; ++w) acc += part[w][st][tid];
            v[st] = acc;
        }
        float mu = v[0] * (1.0f / 512.0f);
        float var = v[1] * (1.0f / 512.0f) - mu * mu;
        float rsig = rsqrtf(var + LN_EPS);
        const float invsq = 0.04419417382415922f;  // 1/sqrt(512)
        float sc[R], mx = -1e30f;
        #pragma unroll
        for (int r = 0; r < R; ++r) {
            float swp = ws[4096 + r], sbp = ws[4104 + r];
            sc[r] = ((v[2 + r] - mu * swp) * rsig + sbp) * invsq;
            mx = fmaxf(mx, sc[r]);
        }
        float es = 0.f, at[R];
        #pragma unroll
        for (int r = 0; r < R; ++r) { at[r] = expf(sc[r] - mx); es += at[r]; }
        float inv = 1.0f / es;
        #pragma unroll
        for (int r = 0; r < R; ++r) attn_s[r][tid] = at[r] * inv;
    }
    __syncthreads();

    #pragma unroll
    for (int r = 0; r < R; ++r) {
        vf2 a = *(const vf2*)&attn_s[r][p2];
        arx[r] = a.x; ary[r] = a.y;
    }

    // ================= epoch D: write h1 =================
    {
        float* ob = ow + n0 + 128 + p2;
        #pragma unroll
        for (int j = 0; j < 32; ++j) {
            const float* mo = Ms + (j << 3);        // wave-uniform -> s_load
            float m0 = mo[0], m1 = mo[1], m2 = mo[2];
            float m3 = mo[3], m4 = mo[4], m5 = mo[5];
            vf2 res;
            res.x = arx[0] * m0 + arx[1] * m1 + arx[2] * m2
                  + arx[3] * m3 + arx[4] * m4 + arx[5] * m5;
            res.y = ary[0] * m0 + ary[1] * m1 + ary[2] * m2
                  + ary[3] * m3 + ary[4] * m4 + ary[5] * m5;
            *(vf2*)(ob + ((size_t)j << 12)) = res;  // L2-absorbed tail
        }
    }
}

extern "C" void kernel_launch(void* const* d_in, const int* in_sizes, int n_in,
                              void* d_out, int out_size, void* d_ws, size_t ws_size,
                              hipStream_t stream) {
    const float* x    = (const float*)d_in[0];
    const float* ln_w = (const float*)d_in[1];
    const float* ln_b = (const float*)d_in[2];
    const float* fc_w = (const float*)d_in[3];
    const float* fc_b = (const float*)d_in[4];
    float* out = (float*)d_out;
    float* ws = (float*)d_ws;

    setup_all<<<O + 1, 64, 0, stream>>>(ln_w, ln_b, fc_w, fc_b, ws);
    fused_kernel<<<BATCH * 16, 1024, 0, stream>>>(x, ws, out);
}

// Round 7
// 231.648 us; speedup vs baseline: 1.2122x; 1.1044x over previous
//
#include <hip/hip_runtime.h>
#include <math.h>

#define C 512
#define NPIX 4096   // 64*64
#define BATCH 16
#define O 512
#define R 6
#define LN_EPS 1e-5f

typedef float vf2 __attribute__((ext_vector_type(2)));

// ws layout (floats):
// [0, 4096)     wpsiT[c*8 + r] = ln_w[c]*psi[r,c]   (r<6; pads 6,7 unused)
// [4096, 4104)  swp[r] = sum_c ln_w[c]*psi[r,c]
// [4104, 4112)  sbp[r] = sum_c ln_b[c]*psi[r,c]
// [4112, 8208)  M[o*8 + r] = sum_c psi[r,c]*fc_w[o,c] + fc_b[o]  (pads 6,7 unused)

__device__ __forceinline__ void hermite_rows(int c, float rows[R]) {
    float t = -1.0f + 2.0f * (float)c / 511.0f;
    float xd = tanhf(t) * 4.31662479035539984911f;  // sqrt(11)+1
    float g = expf(-0.5f * xd * xd);
    const float pi_m14 = 0.75112554446494248286f;   // pi^-0.25
    rows[0] = pi_m14 * g;
    rows[1] = 1.41421356237309504880f * pi_m14 * xd * g;
    #pragma unroll
    for (int k = 2; k <= 5; ++k)
        rows[k] = sqrtf(2.0f / k) * xd * rows[k - 1] - sqrtf((k - 1.0f) / k) * rows[k - 2];
}

// One dispatch for ALL setup. Blocks 0..511: M row o (recompute psi locally).
// Block 512: wpsiT + swp/sbp.
__global__ __launch_bounds__(64) void setup_all(const float* __restrict__ lnw,
                                                const float* __restrict__ lnb,
                                                const float* __restrict__ fcw,
                                                const float* __restrict__ fcb,
                                                float* __restrict__ ws) {
    const int o = blockIdx.x;
    const int l = threadIdx.x;
    if (o < O) {
        float acc[R] = {0.f, 0.f, 0.f, 0.f, 0.f, 0.f};
        #pragma unroll
        for (int k = 0; k < 8; ++k) {
            int c = l + (k << 6);
            float rows[R];
            hermite_rows(c, rows);
            float w = fcw[o * C + c];
            #pragma unroll
            for (int r = 0; r < R; ++r) acc[r] += rows[r] * w;
        }
        #pragma unroll
        for (int r = 0; r < R; ++r)
            #pragma unroll
            for (int m = 32; m >= 1; m >>= 1) acc[r] += __shfl_xor(acc[r], m, 64);
        if (l == 0) {
            float bias = fcb[o];   // softmax weights sum to 1 -> fold bias into M
            float* M = ws + 4112 + o * 8;
            #pragma unroll
            for (int r = 0; r < R; ++r) M[r] = acc[r] + bias;
        }
    } else {
        float sw[R] = {0.f, 0.f, 0.f, 0.f, 0.f, 0.f};
        float sb[R] = {0.f, 0.f, 0.f, 0.f, 0.f, 0.f};
        #pragma unroll
        for (int k = 0; k < 8; ++k) {
            int c = l + (k << 6);
            float rows[R];
            hermite_rows(c, rows);
            float w = lnw[c], bb = lnb[c];
            float* dst = ws + c * 8;
            #pragma unroll
            for (int r = 0; r < R; ++r) {
                float rw = rows[r] * w;
                dst[r] = rw;
                sw[r] += rw;
                sb[r] += rows[r] * bb;
            }
        }
        #pragma unroll
        for (int r = 0; r < R; ++r) {
            #pragma unroll
            for (int m = 32; m >= 1; m >>= 1) {
                sw[r] += __shfl_xor(sw[r], m, 64);
                sb[r] += __shfl_xor(sb[r], m, 64);
            }
        }
        if (l == 0) {
            #pragma unroll
            for (int r = 0; r < R; ++r) { ws[4096 + r] = sw[r]; ws[4104 + r] = sb[r]; }
        }
    }
}

// Fused per-pixel-group kernel — round-1's best-measured shape (79.8 us),
// with NONTEMPORAL x loads. x has zero intra-iteration reuse (each element
// read once), so allocating it through L1/L2/L3 only generates eviction/
// directory traffic against the concurrent output-store stream. The 6.7 TB/s
// reference streams (fills, bcast) are all nt; our cached read stream is the
// lone ~2.5 TB/s outlier. nt loads make the read a pure stream.
// 512 blocks (16 b x 32 groups of 128 px) x 512 threads (8 waves). Wave wv
// owns channels [wv*64, wv*64+64); lane l owns pixels 2l, 2l+1 (float2).
__global__ __launch_bounds__(512) void fused_kernel(const float* __restrict__ x,
                                                    const float* __restrict__ ws,
                                                    float* __restrict__ out) {
    __shared__ float part[8][8][128];   // [wave][stat][px], 32 KB
    __shared__ float attn_s[R][128];    // 3 KB
    const int tid = threadIdx.x;
    const int wv = tid >> 6;
    const int l = tid & 63;
    const int b = blockIdx.x >> 5;
    const int pxg = blockIdx.x & 31;
    const int n0 = pxg << 7;
    const int p2 = l << 1;
    const int wuni = __builtin_amdgcn_readfirstlane(wv);  // force SGPR

    // ---- Phase 1: nontemporal read stream. 64 channels per wave.
    const float* xb = x + (((size_t)(b * C + (wuni << 6))) << 12) + n0 + p2;
    const float* wbase = ws + ((size_t)(wuni << 6) << 3);

    float sx = 0.f, sy = 0.f, ssx = 0.f, ssy = 0.f;
    float a0x = 0.f, a0y = 0.f, a1x = 0.f, a1y = 0.f, a2x = 0.f, a2y = 0.f;
    float a3x = 0.f, a3y = 0.f, a4x = 0.f, a4y = 0.f, a5x = 0.f, a5y = 0.f;
    #pragma unroll 8
    for (int i = 0; i < 64; ++i) {
        vf2 xv = __builtin_nontemporal_load((const vf2*)(xb + ((size_t)i << 12)));
        const float* wr = wbase + (i << 3);     // wave-uniform -> s_load
        float w0 = wr[0], w1 = wr[1], w2 = wr[2];
        float w3 = wr[3], w4 = wr[4], w5 = wr[5];
        sx += xv.x;          sy += xv.y;
        ssx += xv.x * xv.x;  ssy += xv.y * xv.y;
        a0x += xv.x * w0;    a0y += xv.y * w0;
        a1x += xv.x * w1;    a1y += xv.y * w1;
        a2x += xv.x * w2;    a2y += xv.y * w2;
        a3x += xv.x * w3;    a3y += xv.y * w3;
        a4x += xv.x * w4;    a4y += xv.y * w4;
        a5x += xv.x * w5;    a5y += xv.y * w5;
    }
    {
        vf2 t;
        t.x = sx;  t.y = sy;  *(vf2*)&part[wv][0][p2] = t;
        t.x = ssx; t.y = ssy; *(vf2*)&part[wv][1][p2] = t;
        t.x = a0x; t.y = a0y; *(vf2*)&part[wv][2][p2] = t;
        t.x = a1x; t.y = a1y; *(vf2*)&part[wv][3][p2] = t;
        t.x = a2x; t.y = a2y; *(vf2*)&part[wv][4][p2] = t;
        t.x = a3x; t.y = a3y; *(vf2*)&part[wv][5][p2] = t;
        t.x = a4x; t.y = a4y; *(vf2*)&part[wv][6][p2] = t;
        t.x = a5x; t.y = a5y; *(vf2*)&part[wv][7][p2] = t;
    }
    __syncthreads();

    // ---- Combine + softmax (128 threads, one per pixel). attn stays in LDS.
    if (tid < 128) {
        float v[8];
        #pragma unroll
        for (int st = 0; st < 8; ++st) {
            float acc = 0.f;
            #pragma unroll
            for (int w = 0; w < 8; ++w) acc += part[w][st][tid];
            v[st] = acc;
        }
        float mu = v[0] * (1.0f / 512.0f);
        float var = v[1] * (1.0f / 512.0f) - mu * mu;
        float rsig = rsqrtf(var + LN_EPS);
        const float invsq = 0.04419417382415922f;  // 1/sqrt(512)
        float sc[R], mx = -1e30f;
        #pragma unroll
        for (int r = 0; r < R; ++r) {
            float swp = ws[4096 + r], sbp = ws[4104 + r];
            sc[r] = ((v[2 + r] - mu * swp) * rsig + sbp) * invsq;
            mx = fmaxf(mx, sc[r]);
        }
        float es = 0.f, at[R];
        #pragma unroll
        for (int r = 0; r < R; ++r) { at[r] = expf(sc[r] - mx); es += at[r]; }
        float inv = 1.0f / es;
        #pragma unroll
        for (int r = 0; r < R; ++r) attn_s[r][tid] = at[r] * inv;
    }
    __syncthreads();

    // ---- Phase 2: write stream. 64 o-rows per wave, same 2 px per lane.
    float arx[R], ary[R];
    #pragma unroll
    for (int r = 0; r < R; ++r) {
        vf2 a = *(const vf2*)&attn_s[r][p2];
        arx[r] = a.x; ary[r] = a.y;
    }
    const float* Ms = ws + 4112 + ((size_t)(wuni << 6) << 3);
    float* ob = out + (((size_t)(b * O + (wuni << 6))) << 12) + n0 + p2;
    #pragma unroll 8
    for (int j = 0; j < 64; ++j) {
        const float* mo = Ms + (j << 3);        // wave-uniform -> s_load
        float m0 = mo[0], m1 = mo[1], m2 = mo[2];
        float m3 = mo[3], m4 = mo[4], m5 = mo[5];
        vf2 res;
        res.x = arx[0] * m0 + arx[1] * m1 + arx[2] * m2
              + arx[3] * m3 + arx[4] * m4 + arx[5] * m5;
        res.y = ary[0] * m0 + ary[1] * m1 + ary[2] * m2
              + ary[3] * m3 + ary[4] * m4 + ary[5] * m5;
        __builtin_nontemporal_store(res, (vf2*)(ob + ((size_t)j << 12)));
    }
}

extern "C" void kernel_launch(void* const* d_in, const int* in_sizes, int n_in,
                              void* d_out, int out_size, void* d_ws, size_t ws_size,
                              hipStream_t stream) {
    const float* x    = (const float*)d_in[0];
    const float* ln_w = (const float*)d_in[1];
    const float* ln_b = (const float*)d_in[2];
    const float* fc_w = (const float*)d_in[3];
    const float* fc_b = (const float*)d_in[4];
    float* out = (float*)d_out;
    float* ws = (float*)d_ws;

    setup_all<<<O + 1, 64, 0, stream>>>(ln_w, ln_b, fc_w, fc_b, ws);
    fused_kernel<<<BATCH * 32, 512, 0, stream>>>(x, ws, out);
}